// Round 12
// baseline (298.796 us; speedup 1.0000x reference)
//
#include <hip/hip_runtime.h>
#include <hip/hip_bf16.h>
#include <math.h>

#define BB 2
#define SS 2048
#define DD 1024
#define HH 16
#define RR (BB*SS)
#define KSTRIDE 2064   // padded key stride per (b,h)
#define MB (1024ull*1024ull)

typedef unsigned short u16;
typedef unsigned int u32;
typedef __attribute__((ext_vector_type(8))) short short8v;
typedef __attribute__((ext_vector_type(4))) float f32x4;
typedef __attribute__((ext_vector_type(16))) float f32x16;
typedef __attribute__((ext_vector_type(4))) u16 u16x4;

__device__ __forceinline__ u16 f2bf(float f){
    union { __hip_bfloat16 h; u16 u; } c; c.h = __float2bfloat16(f); return c.u;
}
// packed f32x2 -> bf16x2 in one instruction (dst.lo=bf16(a), dst.hi=bf16(b))
__device__ __forceinline__ u32 cvtpk(float a, float b){
    u32 r;
    asm("v_cvt_pk_bf16_f32 %0, %1, %2" : "=v"(r) : "v"(a), "v"(b));
    return r;
}
__device__ __forceinline__ float exp2_raw(float x){
    float r;
    asm("v_exp_f32 %0, %1" : "=v"(r) : "v"(x));
    return r;
}
__device__ __forceinline__ float bf2f(u16 u){
    union { u32 i; float f; } c; c.i = (u32)u << 16; return c.f;
}
// A&S 7.1.26 erf approximation, |err| <= 1.5e-7
__device__ __forceinline__ float erf_fast(float x){
    float ax = fabsf(x);
    float t = __builtin_amdgcn_rcpf(1.0f + 0.3275911f*ax);
    float y = t*(0.254829592f + t*(-0.284496736f + t*(1.421413741f + t*(-1.453152027f + t*1.061405429f))));
    float r = 1.0f - y*__expf(-ax*ax);
    return copysignf(r, x);
}

#define GLL16(gp, lp) __builtin_amdgcn_global_load_lds( \
    (const __attribute__((address_space(1))) void*)(gp), \
    (__attribute__((address_space(3))) void*)(lp), 16, 0, 0)

#define VMCNT8 asm volatile("s_waitcnt vmcnt(8)" ::: "memory")
#define VMCNT4 asm volatile("s_waitcnt vmcnt(4)" ::: "memory")
#define VMCNT0 asm volatile("s_waitcnt vmcnt(0)" ::: "memory")
#define SBAR   __builtin_amdgcn_s_barrier()
#define SCHEDB __builtin_amdgcn_sched_barrier(0)

// ---------------- LayerNorm ----------------
__global__ __launch_bounds__(256) void ln_kernel(const float* __restrict__ in,
    const float* __restrict__ mproj, const float* __restrict__ g, const float* __restrict__ be,
    float* __restrict__ mixed_out, float* __restrict__ outf, u16* __restrict__ outb)
{
    int row = blockIdx.x; int b = row / SS; int tid = threadIdx.x;
    float4 v = ((const float4*)(in + (size_t)row*DD))[tid];
    if (mproj){
        float4 mp = ((const float4*)(mproj + (size_t)b*DD))[tid];
        v.x+=mp.x; v.y+=mp.y; v.z+=mp.z; v.w+=mp.w;
        ((float4*)(mixed_out + (size_t)row*DD))[tid] = v;
    }
    float s = v.x+v.y+v.z+v.w, s2 = v.x*v.x+v.y*v.y+v.z*v.z+v.w*v.w;
    #pragma unroll
    for (int off=32; off>0; off>>=1){ s += __shfl_down(s,off); s2 += __shfl_down(s2,off); }
    __shared__ float red[2][4];
    if ((tid&63)==0){ red[0][tid>>6]=s; red[1][tid>>6]=s2; }
    __syncthreads();
    float st = red[0][0]+red[0][1]+red[0][2]+red[0][3];
    float s2t= red[1][0]+red[1][1]+red[1][2]+red[1][3];
    float mean = st*(1.f/DD); float var = s2t*(1.f/DD)-mean*mean;
    float rs = rsqrtf(var + 1e-5f);
    float4 gg=((const float4*)g)[tid], bb2=((const float4*)be)[tid];
    float o0=(v.x-mean)*rs*gg.x+bb2.x, o1=(v.y-mean)*rs*gg.y+bb2.y;
    float o2=(v.z-mean)*rs*gg.z+bb2.z, o3=(v.w-mean)*rs*gg.w+bb2.w;
    if (outf){ float4 o={o0,o1,o2,o3}; ((float4*)(outf+(size_t)row*DD))[tid]=o; }
    if (outb){ u16x4 o={f2bf(o0),f2bf(o1),f2bf(o2),f2bf(o3)}; ((u16x4*)(outb+(size_t)row*DD))[tid]=o; }
}

// ---------------- final: y = sum(4 bf16 partials)+bias+resid, out = LN(y) ----------------
__global__ __launch_bounds__(256) void ln3f_kernel(const u16* __restrict__ pb0,
    const u16* __restrict__ pb1, const u16* __restrict__ pb2, const u16* __restrict__ pb3,
    const float* __restrict__ bias, const float* __restrict__ resid,
    const float* __restrict__ g, const float* __restrict__ be, float* __restrict__ out)
{
    int row = blockIdx.x; int tid = threadIdx.x;
    size_t off = (size_t)row*DD;
    u16x4 q0 = ((const u16x4*)(pb0+off))[tid];
    u16x4 q1 = ((const u16x4*)(pb1+off))[tid];
    u16x4 q2 = ((const u16x4*)(pb2+off))[tid];
    u16x4 q3 = ((const u16x4*)(pb3+off))[tid];
    float4 bi = ((const float4*)bias)[tid];
    float4 rs4= ((const float4*)(resid+off))[tid];
    float4 v;
    v.x = bf2f(q0[0])+bf2f(q1[0])+bf2f(q2[0])+bf2f(q3[0]) + bi.x + rs4.x;
    v.y = bf2f(q0[1])+bf2f(q1[1])+bf2f(q2[1])+bf2f(q3[1]) + bi.y + rs4.y;
    v.z = bf2f(q0[2])+bf2f(q1[2])+bf2f(q2[2])+bf2f(q3[2]) + bi.z + rs4.z;
    v.w = bf2f(q0[3])+bf2f(q1[3])+bf2f(q2[3])+bf2f(q3[3]) + bi.w + rs4.w;
    float s = v.x+v.y+v.z+v.w, s2 = v.x*v.x+v.y*v.y+v.z*v.z+v.w*v.w;
    #pragma unroll
    for (int off2=32; off2>0; off2>>=1){ s += __shfl_down(s,off2); s2 += __shfl_down(s2,off2); }
    __shared__ float red[2][4];
    if ((tid&63)==0){ red[0][tid>>6]=s; red[1][tid>>6]=s2; }
    __syncthreads();
    float st = red[0][0]+red[0][1]+red[0][2]+red[0][3];
    float s2t= red[1][0]+red[1][1]+red[1][2]+red[1][3];
    float mean = st*(1.f/DD); float var = s2t*(1.f/DD)-mean*mean;
    float rs = rsqrtf(var + 1e-5f);
    float4 gg=((const float4*)g)[tid], bb2=((const float4*)be)[tid];
    float4 o;
    o.x=(v.x-mean)*rs*gg.x+bb2.x; o.y=(v.y-mean)*rs*gg.y+bb2.y;
    o.z=(v.z-mean)*rs*gg.z+bb2.z; o.w=(v.w-mean)*rs*gg.w+bb2.w;
    ((float4*)(out + off))[tid] = o;
}

// ---------------- merged weight transposes ----------------
__global__ __launch_bounds__(256) void tr6_kernel(const float* __restrict__ Wq, const float* __restrict__ Wk,
    const float* __restrict__ Wv, const float* __restrict__ Wo,
    const float* __restrict__ W1, const float* __restrict__ W2,
    u16* __restrict__ WqkvT, u16* __restrict__ WoT, u16* __restrict__ W1T, u16* __restrict__ W2T)
{
    __shared__ float t[32][33];
    int bid = blockIdx.x;
    const float* in; u16* out; int K, N, n0, k0;
    if (bid < 3072){
        int m = bid >> 10, r = bid & 1023;
        in = (m==0) ? Wq : (m==1) ? Wk : Wv;
        out = WqkvT + (size_t)m*1024*1024;
        K = 1024; N = 1024; n0 = (r & 31)*32; k0 = (r >> 5)*32;
    } else if (bid < 4096){
        int r = bid - 3072;
        in = Wo; out = WoT; K = 1024; N = 1024; n0 = (r & 31)*32; k0 = (r >> 5)*32;
    } else if (bid < 8192){
        int r = bid - 4096;
        in = W1; out = W1T; K = 1024; N = 4096; n0 = (r & 127)*32; k0 = (r >> 7)*32;
    } else {
        int r = bid - 8192;
        in = W2; out = W2T; K = 4096; N = 1024; n0 = (r & 31)*32; k0 = (r >> 5)*32;
    }
    int tx = threadIdx.x & 31, ty = threadIdx.x >> 5;
    #pragma unroll
    for (int i=0;i<4;i++){ int k = ty + i*8; t[k][tx] = in[(size_t)(k0+k)*N + n0 + tx]; }
    __syncthreads();
    #pragma unroll
    for (int i=0;i<4;i++){ int n = ty + i*8; out[(size_t)(n0+n)*K + k0 + tx] = f2bf(t[tx][n]); }
}

// =============== 256x256 8-phase GEMM (T2+T3+T4+T5), 512 threads = 8 waves (2M x 4N) ===============
__global__ __launch_bounds__(512) void mgemm256(const u16* __restrict__ A, const u16* __restrict__ BT,
    int nbx, int Kc, int kchunks, int mode, const float* __restrict__ bias, float scale,
    void* __restrict__ Cout, void* __restrict__ C2a, void* __restrict__ C2b, void* __restrict__ C2c)
{
    __shared__ __align__(16) u16 lds[2][2][2][256*32];
    int tid = threadIdx.x, l = tid&63, w = tid>>6;
    int wr = w>>2, wc = w&3;
    int nwg = gridDim.x, q8 = nwg>>3;
    int bid = blockIdx.x;
    int swz = (bid & 7)*q8 + (bid >> 3);
    int tiles = nwg / kchunks;
    int chunk = swz / tiles;
    int t2 = swz % tiles;
    int by = t2 / nbx, bx = t2 % nbx;
    int bm = by*256, bn = bx*256;
    int lda = Kc*kchunks;
    int koff = chunk*Kc;
    const int NT = Kc >> 6;

    f32x4 acc[8][4];
    #pragma unroll
    for (int i=0;i<8;i++)
        #pragma unroll
        for (int j=0;j<4;j++)
            #pragma unroll
            for (int r=0;r<4;r++) acc[i][j][r]=0.f;

    auto stage_plane = [&](int buf, int op, int ks, int tt){
        const u16* base = op ? BT : A;
        int tile0 = op ? bn : bm;
        #pragma unroll
        for (int i=0;i<2;i++){
            int rbase = (w*2+i)*16;
            int row = rbase + (l>>2);
            int slotlog = (l&3) ^ ((row>>1)&3);
            const u16* g = base + (size_t)(tile0 + row)*lda + koff + tt*64 + ks*32 + slotlog*8;
            GLL16(g, (u16*)&lds[buf][op][ks][0] + rbase*32);
        }
    };
    auto ds_a = [&](int buf, int ks, int ai) -> short8v {
        int row = wr*128 + ai*16 + (l&15);
        int slot = (l>>4) ^ ((row>>1)&3);
        return *(const short8v*)((const char*)&lds[buf][0][ks][0] + row*64 + slot*16);
    };
    auto ds_b = [&](int buf, int ks, int bi) -> short8v {
        int row = wc*64 + bi*16 + (l&15);
        int slot = (l>>4) ^ ((row>>1)&3);
        return *(const short8v*)((const char*)&lds[buf][1][ks][0] + row*64 + slot*16);
    };

    stage_plane(0,0,0,0); stage_plane(0,1,0,0);
    stage_plane(0,0,1,0); stage_plane(0,1,1,0);
    stage_plane(1,0,0,1); stage_plane(1,1,0,1);
    VMCNT8;
    SBAR; SCHEDB;

    for (int t=0; t<NT; t++){
        int buf = t&1, obuf = buf^1;
        bool s1 = (t+1 < NT), s2 = (t+2 < NT);
        short8v b0,b1,b2,b3, a0,a1,a2,a3;
        // ---- Ph0
        b0=ds_b(buf,0,0); b1=ds_b(buf,0,1); b2=ds_b(buf,0,2); b3=ds_b(buf,0,3);
        a0=ds_a(buf,0,0); a1=ds_a(buf,0,1); a2=ds_a(buf,0,2); a3=ds_a(buf,0,3);
        if (s1) stage_plane(obuf,0,1,t+1);
        __builtin_amdgcn_s_setprio(1);
        acc[0][0]=__builtin_amdgcn_mfma_f32_16x16x32_bf16(b0,a0,acc[0][0],0,0,0);
        acc[0][1]=__builtin_amdgcn_mfma_f32_16x16x32_bf16(b1,a0,acc[0][1],0,0,0);
        acc[0][2]=__builtin_amdgcn_mfma_f32_16x16x32_bf16(b2,a0,acc[0][2],0,0,0);
        acc[0][3]=__builtin_amdgcn_mfma_f32_16x16x32_bf16(b3,a0,acc[0][3],0,0,0);
        acc[1][0]=__builtin_amdgcn_mfma_f32_16x16x32_bf16(b0,a1,acc[1][0],0,0,0);
        acc[1][1]=__builtin_amdgcn_mfma_f32_16x16x32_bf16(b1,a1,acc[1][1],0,0,0);
        acc[1][2]=__builtin_amdgcn_mfma_f32_16x16x32_bf16(b2,a1,acc[1][2],0,0,0);
        acc[1][3]=__builtin_amdgcn_mfma_f32_16x16x32_bf16(b3,a1,acc[1][3],0,0,0);
        acc[2][0]=__builtin_amdgcn_mfma_f32_16x16x32_bf16(b0,a2,acc[2][0],0,0,0);
        acc[2][1]=__builtin_amdgcn_mfma_f32_16x16x32_bf16(b1,a2,acc[2][1],0,0,0);
        acc[2][2]=__builtin_amdgcn_mfma_f32_16x16x32_bf16(b2,a2,acc[2][2],0,0,0);
        acc[2][3]=__builtin_amdgcn_mfma_f32_16x16x32_bf16(b3,a2,acc[2][3],0,0,0);
        acc[3][0]=__builtin_amdgcn_mfma_f32_16x16x32_bf16(b0,a3,acc[3][0],0,0,0);
        acc[3][1]=__builtin_amdgcn_mfma_f32_16x16x32_bf16(b1,a3,acc[3][1],0,0,0);
        acc[3][2]=__builtin_amdgcn_mfma_f32_16x16x32_bf16(b2,a3,acc[3][2],0,0,0);
        acc[3][3]=__builtin_amdgcn_mfma_f32_16x16x32_bf16(b3,a3,acc[3][3],0,0,0);
        __builtin_amdgcn_s_setprio(0);
        SBAR; SCHEDB;
        // ---- Ph1
        a0=ds_a(buf,0,4); a1=ds_a(buf,0,5); a2=ds_a(buf,0,6); a3=ds_a(buf,0,7);
        if (s1) stage_plane(obuf,1,1,t+1);
        __builtin_amdgcn_s_setprio(1);
        acc[4][0]=__builtin_amdgcn_mfma_f32_16x16x32_bf16(b0,a0,acc[4][0],0,0,0);
        acc[4][1]=__builtin_amdgcn_mfma_f32_16x16x32_bf16(b1,a0,acc[4][1],0,0,0);
        acc[4][2]=__builtin_amdgcn_mfma_f32_16x16x32_bf16(b2,a0,acc[4][2],0,0,0);
        acc[4][3]=__builtin_amdgcn_mfma_f32_16x16x32_bf16(b3,a0,acc[4][3],0,0,0);
        acc[5][0]=__builtin_amdgcn_mfma_f32_16x16x32_bf16(b0,a1,acc[5][0],0,0,0);
        acc[5][1]=__builtin_amdgcn_mfma_f32_16x16x32_bf16(b1,a1,acc[5][1],0,0,0);
        acc[5][2]=__builtin_amdgcn_mfma_f32_16x16x32_bf16(b2,a1,acc[5][2],0,0,0);
        acc[5][3]=__builtin_amdgcn_mfma_f32_16x16x32_bf16(b3,a1,acc[5][3],0,0,0);
        acc[6][0]=__builtin_amdgcn_mfma_f32_16x16x32_bf16(b0,a2,acc[6][0],0,0,0);
        acc[6][1]=__builtin_amdgcn_mfma_f32_16x16x32_bf16(b1,a2,acc[6][1],0,0,0);
        acc[6][2]=__builtin_amdgcn_mfma_f32_16x16x32_bf16(b2,a2,acc[6][2],0,0,0);
        acc[6][3]=__builtin_amdgcn_mfma_f32_16x16x32_bf16(b3,a2,acc[6][3],0,0,0);
        acc[7][0]=__builtin_amdgcn_mfma_f32_16x16x32_bf16(b0,a3,acc[7][0],0,0,0);
        acc[7][1]=__builtin_amdgcn_mfma_f32_16x16x32_bf16(b1,a3,acc[7][1],0,0,0);
        acc[7][2]=__builtin_amdgcn_mfma_f32_16x16x32_bf16(b2,a3,acc[7][2],0,0,0);
        acc[7][3]=__builtin_amdgcn_mfma_f32_16x16x32_bf16(b3,a3,acc[7][3],0,0,0);
        __builtin_amdgcn_s_setprio(0);
        if (s1) { VMCNT8; } else { VMCNT0; }
        SBAR; SCHEDB;
        // ---- Ph2
        b0=ds_b(buf,1,0); b1=ds_b(buf,1,1); b2=ds_b(buf,1,2); b3=ds_b(buf,1,3);
        a0=ds_a(buf,1,0); a1=ds_a(buf,1,1); a2=ds_a(buf,1,2); a3=ds_a(buf,1,3);
        if (s2) stage_plane(buf,0,0,t+2);
        __builtin_amdgcn_s_setprio(1);
        acc[0][0]=__builtin_amdgcn_mfma_f32_16x16x32_bf16(b0,a0,acc[0][0],0,0,0);
        acc[0][1]=__builtin_amdgcn_mfma_f32_16x16x32_bf16(b1,a0,acc[0][1],0,0,0);
        acc[0][2]=__builtin_amdgcn_mfma_f32_16x16x32_bf16(b2,a0,acc[0][2],0,0,0);
        acc[0][3]=__builtin_amdgcn_mfma_f32_16x16x32_bf16(b3,a0,acc[0][3],0,0,0);
        acc[1][0]=__builtin_amdgcn_mfma_f32_16x16x32_bf16(b0,a1,acc[1][0],0,0,0);
        acc[1][1]=__builtin_amdgcn_mfma_f32_16x16x32_bf16(b1,a1,acc[1][1],0,0,0);
        acc[1][2]=__builtin_amdgcn_mfma_f32_16x16x32_bf16(b2,a1,acc[1][2],0,0,0);
        acc[1][3]=__builtin_amdgcn_mfma_f32_16x16x32_bf16(b3,a1,acc[1][3],0,0,0);
        acc[2][0]=__builtin_amdgcn_mfma_f32_16x16x32_bf16(b0,a2,acc[2][0],0,0,0);
        acc[2][1]=__builtin_amdgcn_mfma_f32_16x16x32_bf16(b1,a2,acc[2][1],0,0,0);
        acc[2][2]=__builtin_amdgcn_mfma_f32_16x16x32_bf16(b2,a2,acc[2][2],0,0,0);
        acc[2][3]=__builtin_amdgcn_mfma_f32_16x16x32_bf16(b3,a2,acc[2][3],0,0,0);
        acc[3][0]=__builtin_amdgcn_mfma_f32_16x16x32_bf16(b0,a3,acc[3][0],0,0,0);
        acc[3][1]=__builtin_amdgcn_mfma_f32_16x16x32_bf16(b1,a3,acc[3][1],0,0,0);
        acc[3][2]=__builtin_amdgcn_mfma_f32_16x16x32_bf16(b2,a3,acc[3][2],0,0,0);
        acc[3][3]=__builtin_amdgcn_mfma_f32_16x16x32_bf16(b3,a3,acc[3][3],0,0,0);
        __builtin_amdgcn_s_setprio(0);
        SBAR; SCHEDB;
        // ---- Ph3
        a0=ds_a(buf,1,4); a1=ds_a(buf,1,5); a2=ds_a(buf,1,6); a3=ds_a(buf,1,7);
        if (s2) stage_plane(buf,1,0,t+2);
        __builtin_amdgcn_s_setprio(1);
        acc[4][0]=__builtin_amdgcn_mfma_f32_16x16x32_bf16(b0,a0,acc[4][0],0,0,0);
        acc[4][1]=__builtin_amdgcn_mfma_f32_16x16x32_bf16(b1,a0,acc[4][1],0,0,0);
        acc[4][2]=__builtin_amdgcn_mfma_f32_16x16x32_bf16(b2,a0,acc[4][2],0,0,0);
        acc[4][3]=__builtin_amdgcn_mfma_f32_16x16x32_bf16(b3,a0,acc[4][3],0,0,0);
        acc[5][0]=__builtin_amdgcn_mfma_f32_16x16x32_bf16(b0,a1,acc[5][0],0,0,0);
        acc[5][1]=__builtin_amdgcn_mfma_f32_16x16x32_bf16(b1,a1,acc[5][1],0,0,0);
        acc[5][2]=__builtin_amdgcn_mfma_f32_16x16x32_bf16(b2,a1,acc[5][2],0,0,0);
        acc[5][3]=__builtin_amdgcn_mfma_f32_16x16x32_bf16(b3,a1,acc[5][3],0,0,0);
        acc[6][0]=__builtin_amdgcn_mfma_f32_16x16x32_bf16(b0,a2,acc[6][0],0,0,0);
        acc[6][1]=__builtin_amdgcn_mfma_f32_16x16x32_bf16(b1,a2,acc[6][1],0,0,0);
        acc[6][2]=__builtin_amdgcn_mfma_f32_16x16x32_bf16(b2,a2,acc[6][2],0,0,0);
        acc[6][3]=__builtin_amdgcn_mfma_f32_16x16x32_bf16(b3,a2,acc[6][3],0,0,0);
        acc[7][0]=__builtin_amdgcn_mfma_f32_16x16x32_bf16(b0,a3,acc[7][0],0,0,0);
        acc[7][1]=__builtin_amdgcn_mfma_f32_16x16x32_bf16(b1,a3,acc[7][1],0,0,0);
        acc[7][2]=__builtin_amdgcn_mfma_f32_16x16x32_bf16(b2,a3,acc[7][2],0,0,0);
        acc[7][3]=__builtin_amdgcn_mfma_f32_16x16x32_bf16(b3,a3,acc[7][3],0,0,0);
        __builtin_amdgcn_s_setprio(0);
        if (s2) { VMCNT8; } else if (s1) { VMCNT4; } else { VMCNT0; }
        SBAR; SCHEDB;
    }

    int N = nbx*256;
    #pragma unroll
    for (int ai=0; ai<8; ai++){
        int m = bm + wr*128 + ai*16 + (l&15);
        #pragma unroll
        for (int bi=0; bi<4; bi++){
            int nb = bn + wc*64 + bi*16 + ((l>>4)<<2);
            f32x4 v = acc[ai][bi];
            if (mode == 0){   // GELU bf16
                float4 bv = *(const float4*)(bias + nb);
                float t0=v[0]+bv.x, t1=v[1]+bv.y, t2=v[2]+bv.z, t3=v[3]+bv.w;
                u16x4 o;
                o[0]=f2bf(0.5f*t0*(1.0f+erf_fast(t0*0.70710678118654752f)));
                o[1]=f2bf(0.5f*t1*(1.0f+erf_fast(t1*0.70710678118654752f)));
                o[2]=f2bf(0.5f*t2*(1.0f+erf_fast(t2*0.70710678118654752f)));
                o[3]=f2bf(0.5f*t3*(1.0f+erf_fast(t3*0.70710678118654752f)));
                *(u16x4*)((u16*)Cout + (size_t)m*N + nb) = o;
            } else if (mode == 1){  // QKV
                if (nb < 1024){
                    u16x4 o;
                    #pragma unroll
                    for (int r=0;r<4;r++) o[r] = f2bf(v[r]*scale);
                    *(u16x4*)((u16*)Cout + (size_t)m*1024 + nb) = o;
                } else if (nb < 2048){
                    int cc = nb-1024; int hh = cc>>6, dh = cc&63;
                    int b2 = m>>11, key = m&2047;
                    u16x4 o;
                    #pragma unroll
                    for (int r=0;r<4;r++) o[r] = f2bf(v[r]);
                    *(u16x4*)((u16*)C2a + ((size_t)(b2*HH+hh)*KSTRIDE + key)*64 + dh) = o;
                } else {
                    int cc = nb-2048; int hh = cc>>6, dh = cc&63;
                    int b2 = m>>11, key = m&2047;
                    #pragma unroll
                    for (int r=0;r<4;r++)
                        ((u16*)C2b)[((size_t)(b2*HH+hh)*64 + dh + r)*KSTRIDE + key] = f2bf(v[r]);
                }
            } else {          // mode 2: bf16 partial per chunk
                u16* pp = (chunk==0) ? (u16*)Cout : (chunk==1) ? (u16*)C2a :
                          (chunk==2) ? (u16*)C2b : (u16*)C2c;
                u16x4 o;
                #pragma unroll
                for (int r=0;r<4;r++) o[r] = f2bf(v[r]);
                *(u16x4*)(pp + (size_t)m*N + nb) = o;
            }
        }
    }
}

// ---------------- 128x128 MFMA GEMM (kept for Wo) ----------------
#define MODE_F32R 3

__global__ __launch_bounds__(256) void mgemm(const u16* __restrict__ A, const u16* __restrict__ BT,
    int nbx, int Kc, int kchunks, int mode,
    const float* __restrict__ bias, const float* __restrict__ resid, float scale,
    void* __restrict__ Cout, void* __restrict__ C2a, void* __restrict__ C2b)
{
    int tid=threadIdx.x, l=tid&63, w=tid>>6;
    int nwg = gridDim.x;
    int qq = nwg >> 3;
    int bid = blockIdx.x;
    int swz = (bid & 7)*qq + (bid >> 3);
    int tiles = nwg / kchunks;
    int chunk = swz / tiles;
    int t2 = swz % tiles;
    int sby = t2 / (nbx*8);
    int rem = t2 - sby*(nbx*8);
    int sbx = rem >> 6;
    int ci  = rem & 63;
    int bx = sbx*8 + (ci&7);
    int by = sby*8 + (ci>>3);

    int bm = by*128, bn = bx*128;
    int N = nbx*128;
    int lda = Kc*kchunks;
    int koff = chunk*Kc;
    int wr = w>>1, wc = w&1;
    f32x4 acc[4][4];
    #pragma unroll
    for(int i=0;i<4;i++)
        #pragma unroll
        for(int j=0;j<4;j++)
            #pragma unroll
            for(int r=0;r<4;r++) acc[i][j][r]=0.f;

    __shared__ __align__(16) u16 Al[2][4096];
    __shared__ __align__(16) u16 Bl[2][4096];
    int srow = (w<<4) + (l>>2);
    int sph  = l&3;
    const int NT = Kc >> 5;

    auto stage = [&](int buf, int kt){
        #pragma unroll
        for (int r=0;r<2;r++){
            int rowA = srow + r*64;
            int sl = sph ^ ((rowA>>1)&3);
            const u16* gA = A + (size_t)(bm+rowA)*lda + koff + kt*32 + sl*8;
            GLL16(gA, (char*)&Al[buf][0] + r*4096 + w*1024);
            const u16* gB = BT + (size_t)(bn+rowA)*lda + koff + kt*32 + sl*8;
            GLL16(gB, (char*)&Bl[buf][0] + r*4096 + w*1024);
        }
    };

    int cur=0;
    stage(0,0);
    __syncthreads();
    for (int kt=0; kt<NT; kt++){
        if (kt+1<NT) stage(cur^1, kt+1);
        short8v af[4], bf[4];
        #pragma unroll
        for (int mi=0;mi<4;mi++){
            int row = wr*64 + mi*16 + (l&15);
            int sl = (l>>4) ^ ((row>>1)&3);
            af[mi] = *(const short8v*)((const char*)&Al[cur][0] + row*64 + sl*16);
        }
        #pragma unroll
        for (int ni=0;ni<4;ni++){
            int row = wc*64 + ni*16 + (l&15);
            int sl = (l>>4) ^ ((row>>1)&3);
            bf[ni] = *(const short8v*)((const char*)&Bl[cur][0] + row*64 + sl*16);
        }
        #pragma unroll
        for (int mi=0;mi<4;mi++)
            #pragma unroll
            for (int ni=0;ni<4;ni++)
                acc[mi][ni] = __builtin_amdgcn_mfma_f32_16x16x32_bf16(bf[ni], af[mi], acc[mi][ni], 0,0,0);
        __syncthreads();
        cur ^= 1;
    }

    #pragma unroll
    for (int mi=0;mi<4;mi++){
        int m = bm + wr*64 + mi*16 + (l&15);
        #pragma unroll
        for (int ni=0;ni<4;ni++){
            int nb = bn + wc*64 + ni*16 + ((l>>4)<<2);
            f32x4 v = acc[mi][ni];
            float4 rs = *(const float4*)(resid + (size_t)m*N + nb);
            float4 o = {v[0]+rs.x, v[1]+rs.y, v[2]+rs.z, v[3]+rs.w};
            *(float4*)((float*)Cout + (size_t)m*N + nb) = o;
        }
    }
}

// ---------------- MFMA flash attention: barrier-free wave-private K/V, 32-key tiles ----------------
// Each wave owns 32 q-rows and its own LDS region; no __syncthreads in the loop.
__global__ __launch_bounds__(256) void attn_mfma(const u16* __restrict__ Qb, const u16* __restrict__ Kb,
    const u16* __restrict__ VTb, u16* __restrict__ ao)
{
    __shared__ __align__(16) u16 KV[4][2][2][2048];  // [wave][buf][K/V][4KB]
    int tid=threadIdx.x, l=tid&63, w=tid>>6;
    int l31=l&31, hi=l>>5;
    int bid = blockIdx.x;
    int xcd = bid & 7, idx = bid >> 3;
    int bh = xcd*4 + (idx>>4);
    int qt = idx & 15;
    int b=bh>>4, h=bh&15;
    int qrow = qt*128 + w*32 + l31;

    const u16* qptr = Qb + (size_t)(b*SS + qrow)*DD + h*64;
    short8v qf[4];
    #pragma unroll
    for (int t=0;t<4;t++) qf[t] = *(const short8v*)(qptr + t*16 + hi*8);

    f32x16 so0, so1;
    #pragma unroll
    for (int i=0;i<16;i++){ so0[i]=0.f; so1[i]=0.f; }
    float l_run=0.f;

    // stage one 32-key tile (K: [32 keys][64 dh], V^T: [64 dh][32 keys]) into wave-private LDS
    auto stage = [&](int buf, int kt){
        #pragma unroll
        for (int i=0;i<4;i++){       // K: 4 issues x 8 rows (128B rows, 8 slots)
            int row = i*8 + (l>>3);
            int slot = (l&7) ^ (row&7);
            const u16* gK = Kb + ((size_t)bh*KSTRIDE + kt*32 + row)*64 + slot*8;
            GLL16(gK, (u16*)&KV[w][buf][0][0] + i*512);
        }
        #pragma unroll
        for (int i=0;i<4;i++){       // V: 4 issues x 16 rows (64B rows, 4 slots)
            int row = i*16 + (l>>2);
            int slot = (l&3) ^ (row&3);
            const u16* gV = VTb + ((size_t)bh*64 + row)*KSTRIDE + kt*32 + slot*8;
            GLL16(gV, (u16*)&KV[w][buf][1][0] + i*512);
        }
    };

    stage(0, 0);
    const int NT32 = 65;   // 65 tiles of 32 keys cover 2049 (tail masked)
    #pragma unroll 1
    for (int t=0; t<NT32; t++){
        int buf = t&1;
        if (t+1 < NT32){ stage(buf^1, t+1); VMCNT8; } else { VMCNT0; }
        SCHEDB;
        // QK: scores for 32 keys x 32 q-rows
        f32x16 ss;
        #pragma unroll
        for (int i=0;i<16;i++) ss[i]=0.f;
        __builtin_amdgcn_s_setprio(1);
        #pragma unroll
        for (int tt=0;tt<4;tt++){
            int sl = (2*tt+hi) ^ (l31&7);
            short8v kf = *(const short8v*)((const char*)&KV[w][buf][0][0] + l31*128 + sl*16);
            ss = __builtin_amdgcn_mfma_f32_32x32x16_bf16(kf, qf[tt], ss, 0,0,0);
        }
        __builtin_amdgcn_s_setprio(0);
        if (t == NT32-1){
            #pragma unroll
            for (int r=0;r<16;r++){
                int k0 = 2048 + (r&3) + 8*(r>>2) + 4*hi;
                if (k0 >= 2049) ss[r] = -1e30f;
            }
        }
        // softmax (no-max exp2) + P pack + PV
        float psum = 0.f;
        #pragma unroll
        for (int r=0;r<16;r++){ float p=exp2_raw(ss[r]); ss[r]=p; psum+=p; }
        psum += __shfl_xor(psum, 32);
        l_run += psum;
        short8v pf[2];
        #pragma unroll
        for (int tt=0;tt<2;tt++){
            u32 a0,a1,b0,b1;
            if (tt==0){ a0=cvtpk(ss[0],ss[1]);  a1=cvtpk(ss[2],ss[3]);   b0=cvtpk(ss[4],ss[5]);   b1=cvtpk(ss[6],ss[7]); }
            else      { a0=cvtpk(ss[8],ss[9]);  a1=cvtpk(ss[10],ss[11]); b0=cvtpk(ss[12],ss[13]); b1=cvtpk(ss[14],ss[15]); }
            union { u32 u[4]; short8v v; } cvt;
#if __has_builtin(__builtin_amdgcn_permlane32_swap)
            auto r0 = __builtin_amdgcn_permlane32_swap(a0, b0, false, false);
            auto r1 = __builtin_amdgcn_permlane32_swap(a1, b1, false, false);
            cvt.u[0] = (u32)r0[0];
            cvt.u[1] = (u32)r1[0];
            cvt.u[2] = (u32)r0[1];
            cvt.u[3] = (u32)r1[1];
#else
            u32 sx0 = hi ? a0 : b0, sx1 = hi ? a1 : b1;
            u32 r0 = (u32)__shfl_xor((int)sx0, 32);
            u32 r1 = (u32)__shfl_xor((int)sx1, 32);
            cvt.u[0] = hi ? r0 : a0;
            cvt.u[1] = hi ? r1 : a1;
            cvt.u[2] = hi ? b0 : r0;
            cvt.u[3] = hi ? b1 : r1;
#endif
            pf[tt] = cvt.v;
        }
        __builtin_amdgcn_s_setprio(1);
        #pragma unroll
        for (int tt=0;tt<2;tt++){
            int sl = (2*tt+hi) ^ (l31&3);
            short8v vf0 = *(const short8v*)((const char*)&KV[w][buf][1][0] + l31*64 + sl*16);
            so0 = __builtin_amdgcn_mfma_f32_32x32x16_bf16(vf0, pf[tt], so0, 0,0,0);
            short8v vf1 = *(const short8v*)((const char*)&KV[w][buf][1][0] + (32+l31)*64 + sl*16);
            so1 = __builtin_amdgcn_mfma_f32_32x32x16_bf16(vf1, pf[tt], so1, 0,0,0);
        }
        __builtin_amdgcn_s_setprio(0);
    }

    float inv = 1.f / l_run;
    u16* aop = ao + (size_t)(b*SS + qrow)*DD + h*64;
    #pragma unroll
    for (int rg=0; rg<4; rg++){
        int dh0 = rg*8 + 4*hi;
        u16x4 o0, o1;
        #pragma unroll
        for (int j=0;j<4;j++){ o0[j]=f2bf(so0[rg*4+j]*inv); o1[j]=f2bf(so1[rg*4+j]*inv); }
        *(u16x4*)(aop + dh0) = o0;
        *(u16x4*)(aop + 32 + dh0) = o1;
    }
}

// ---------------- split-K matvec ----------------
__global__ __launch_bounds__(256) void vecmat_part(const float* __restrict__ vec,
    const float* __restrict__ W, float* __restrict__ part, int K, int N)
{
    int b = blockIdx.z, kc = blockIdx.y;
    int j = blockIdx.x*256 + threadIdx.x;
    int k0 = kc * (K >> 3);
    float acc = 0.0f;
    #pragma unroll 4
    for (int k = k0; k < k0 + (K >> 3); k++)
        acc += vec[(size_t)b*K + k] * W[(size_t)k*N + j];
    part[((size_t)b*8 + kc)*N + j] = acc;
}

__global__ __launch_bounds__(256) void vecmat_red(const float* __restrict__ part,
    float* __restrict__ out, int N)
{
    int b = blockIdx.y;
    int j = blockIdx.x*256 + threadIdx.x;
    float acc = 0.0f;
    #pragma unroll
    for (int kc = 0; kc < 8; kc++) acc += part[((size_t)b*8 + kc)*N + j];
    out[(size_t)b*N + j] = acc;
}

__global__ __launch_bounds__(256) void vecmat2_part(const float* __restrict__ vec,
    const float* __restrict__ Wa, const float* __restrict__ Wb, float* __restrict__ part)
{
    int b = blockIdx.z, kc = blockIdx.y;
    int j = blockIdx.x*256 + threadIdx.x;
    int k0 = kc * 128;
    float accA = 0.0f, accB = 0.0f;
    #pragma unroll 4
    for (int k = k0; k < k0 + 128; k++){
        float v = vec[(size_t)b*DD + k];
        accA += v * Wa[(size_t)k*DD + j];
        accB += v * Wb[(size_t)k*DD + j];
    }
    part[((size_t)b*8 + kc)*2048 + j] = accA;
    part[((size_t)b*8 + kc)*2048 + 1024 + j] = accB;
}

__global__ __launch_bounds__(256) void vecmat2_red(const float* __restrict__ part,
    float* __restrict__ outA, float* __restrict__ outB)
{
    int b = blockIdx.y;
    int j = blockIdx.x*256 + threadIdx.x;
    float accA = 0.0f, accB = 0.0f;
    #pragma unroll
    for (int kc = 0; kc < 8; kc++){
        accA += part[((size_t)b*8 + kc)*2048 + j];
        accB += part[((size_t)b*8 + kc)*2048 + 1024 + j];
    }
    outA[(size_t)b*DD + j] = accA;
    outB[(size_t)b*DD + j] = accB;
}

__global__ __launch_bounds__(256) void fixup_kernel(const float* __restrict__ Kmb,
    const float* __restrict__ Vmb, u16* __restrict__ Kb, u16* __restrict__ VTb)
{
    int idx = blockIdx.x*256 + threadIdx.x;
    int b = idx>>10, j = idx&1023; int h=j>>6, dh=j&63; int bh=b*HH+h;
    Kb[((size_t)bh*KSTRIDE + 2048)*64 + dh] = f2bf(Kmb[idx]);
    VTb[((size_t)bh*64 + dh)*KSTRIDE + 2048] = f2bf(Vmb[idx]);
}

__global__ __launch_bounds__(256) void pool1_kernel(const float* __restrict__ att, float* __restrict__ ppart)
{
    int b = blockIdx.y, sc = blockIdx.x;
    int tid = threadIdx.x;
    float4 acc = {0,0,0,0};
    for (int s = 0; s < 32; s++) {
        int row = b*SS + sc*32 + s;
        float4 v = ((const float4*)(att + (size_t)row*DD))[tid];
        acc.x += v.x; acc.y += v.y; acc.z += v.z; acc.w += v.w;
    }
    ((float4*)(ppart + ((size_t)b*64 + sc)*DD))[tid] = acc;
}

__global__ __launch_bounds__(256) void pool2_kernel(const float* __restrict__ ppart, float* __restrict__ pooled)
{
    int b = blockIdx.y;
    int j = blockIdx.x*256 + threadIdx.x;
    float acc = 0.0f;
    for (int sc = 0; sc < 64; sc++) acc += ppart[((size_t)b*64 + sc)*DD + j];
    pooled[(size_t)b*DD + j] = acc * (1.0f/SS);
}

__global__ __launch_bounds__(256) void gates_part(const float* __restrict__ pooled,
    const float* __restrict__ h, const float* __restrict__ Wih, const float* __restrict__ Whh,
    float* __restrict__ part)
{
    int b = blockIdx.z, kc = blockIdx.y;
    int j = blockIdx.x*256 + threadIdx.x;
    int k0 = kc * 64;
    float acc = 0.0f;
    #pragma unroll 4
    for (int k = k0; k < k0 + 64; k++)
        acc += pooled[(size_t)b*DD + k] * Wih[(size_t)k*4*DD + j]
             + h[(size_t)b*DD + k]      * Whh[(size_t)k*4*DD + j];
    part[((size_t)b*16 + kc)*4*DD + j] = acc;
}

__device__ __forceinline__ float sigmoidf_(float x) { return 1.0f / (1.0f + __expf(-x)); }

__global__ __launch_bounds__(256) void lstm_kernel(const float* __restrict__ gpart,
    const float* __restrict__ b_ih, const float* __restrict__ b_hh,
    const float* __restrict__ c, float* __restrict__ newh_ws, float* __restrict__ out_tail)
{
    int idx = blockIdx.x*256 + threadIdx.x;
    int b = idx >> 10, d = idx & 1023;
    float sI = b_ih[d]          + b_hh[d];
    float sF = b_ih[DD + d]     + b_hh[DD + d];
    float sG = b_ih[2*DD + d]   + b_hh[2*DD + d];
    float sO = b_ih[3*DD + d]   + b_hh[3*DD + d];
    #pragma unroll
    for (int kc = 0; kc < 16; kc++){
        const float* gp = gpart + ((size_t)b*16 + kc)*4*DD;
        sI += gp[d]; sF += gp[DD + d]; sG += gp[2*DD + d]; sO += gp[3*DD + d];
    }
    float ig = sigmoidf_(sI);
    float fg = sigmoidf_(sF);
    float gg = tanhf(sG);
    float og = sigmoidf_(sO);
    float nc = fg * c[idx] + ig * gg;
    float nh = og * tanhf(nc);
    newh_ws[idx] = nh;
    out_tail[idx] = nh;
    out_tail[BB*DD + idx] = nc;
}

// ---------------- launch ----------------
extern "C" void kernel_launch(void* const* d_in, const int* in_sizes, int n_in,
                              void* d_out, int out_size, void* d_ws, size_t ws_size,
                              hipStream_t stream) {
    const float* x    = (const float*)d_in[0];
    const float* h    = (const float*)d_in[1];
    const float* c    = (const float*)d_in[2];
    const float* Wq   = (const float*)d_in[3];
    const float* Wk   = (const float*)d_in[4];
    const float* Wv   = (const float*)d_in[5];
    const float* Wo   = (const float*)d_in[6];
    const float* Wmk  = (const float*)d_in[7];
    const float* Wmv  = (const float*)d_in[8];
    const float* Wih  = (const float*)d_in[9];
    const float* Whh  = (const float*)d_in[10];
    const float* b_ih = (const float*)d_in[11];
    const float* b_hh = (const float*)d_in[12];
    const float* W1   = (const float*)d_in[13];
    const float* bf1  = (const float*)d_in[14];
    const float* W2   = (const float*)d_in[15];
    const float* bf2  = (const float*)d_in[16];
    const float* g1   = (const float*)d_in[17];
    const float* be1  = (const float*)d_in[18];
    const float* g2   = (const float*)d_in[19];
    const float* be2  = (const float*)d_in[20];
    const float* g3   = (const float*)d_in[21];
    const float* be3  = (const float*)d_in[22];
    const float* Wmp  = (const float*)d_in[23];

    float* out = (float*)d_out;
    char* wsb  = (char*)d_ws;

    u16*   xn   = (u16*)(wsb + 0);        // 8MB  [0,8)
    u16*   hn   = (u16*)(wsb + 8*MB);     // 8MB  [8,16)
    u16*   pb0  = (u16*)(wsb + 0);        // FFN2 partial (xn dead)
    u16*   pb1  = (u16*)(wsb + 8*MB);     // FFN2 partial (hn dead)
    u16*   Qbuf = (u16*)(wsb + 16*MB);
    u16*   Kbuf = (u16*)(wsb + 24*MB);
    u16*   VTb  = (u16*)(wsb + 33*MB);
    u16*   act  = (u16*)(wsb + 16*MB);    // 32MB overlay [16,48)
    u16*   ao   = (u16*)(wsb + 48*MB);    // 8MB
    u16*   pb2  = (u16*)(wsb + 48*MB);    // FFN2 partial (ao dead)
    float* attb = (float*)(wsb + 56*MB);  // 16MB [56,72)
    u16*   WqkvT= (u16*)(wsb + 72*MB);    // 6MB
    u16*   WoT  = (u16*)(wsb + 78*MB);    // 2MB
    u16*   W1T  = (u16*)(wsb + 80*MB);    // 8MB
    u16*   pb3  = (u16*)(wsb + 80*MB);    // FFN2 partial (W1T dead)
    u16*   W2T  = (u16*)(wsb + 88*MB);    // 8MB
    float* sm   = (float*)(wsb + 96*MB);
    float* Kmb     = sm;
    float* Vmb     = Kmb + 2048;
    float* pooled  = Vmb + 2048;
    float* newh    = pooled + 2048;
    float* mproj   = newh + 2048;
    float* vpart   = mproj + 2048;
    float* v2part  = vpart + 16384;
    float* gpart   = v2part + 32768;
    float* ppart   = gpart + 131072;

    tr6_kernel<<<12288, 256, 0, stream>>>(Wq, Wk, Wv, Wo, W1, W2, WqkvT, WoT, W1T, W2T);

    ln_kernel<<<RR, 256, 0, stream>>>(x, nullptr, g1, be1, nullptr, nullptr, xn);
    vecmat2_part<<<dim3(4,8,BB), 256, 0, stream>>>(h, Wmk, Wmv, v2part);
    vecmat2_red<<<dim3(4,BB), 256, 0, stream>>>(v2part, Kmb, Vmb);
    // fused QKV projection: 256^2 8-phase, M=4096 N=3072 K=1024 -> grid 192
    mgemm256<<<192, 512, 0, stream>>>(xn, WqkvT, 12, 1024, 1, 1, nullptr,
                                      0.125f*1.44269504088896f, Qbuf, Kbuf, VTb, nullptr);
    fixup_kernel<<<8, 256, 0, stream>>>(Kmb, Vmb, Kbuf, VTb);
    // attention (512 blocks, XCD-grouped, barrier-free wave-private)
    attn_mfma<<<512, 256, 0, stream>>>(Qbuf, Kbuf, VTb, ao);
    // attended = x + ao @ Wo (128^2 path)
    mgemm<<<8*32, 256, 0, stream>>>(ao, WoT, 8, 1024, 1, MODE_F32R, nullptr, x, 1.f, attb, nullptr, nullptr);
    pool1_kernel<<<dim3(64,BB), 256, 0, stream>>>(attb, ppart);
    pool2_kernel<<<dim3(4,BB), 256, 0, stream>>>(ppart, pooled);
    gates_part<<<dim3(16,16,BB), 256, 0, stream>>>(pooled, h, Wih, Whh, gpart);
    lstm_kernel<<<8, 256, 0, stream>>>(gpart, b_ih, b_hh, c, newh, out + (size_t)RR*DD);
    vecmat_part<<<dim3(4,8,BB), 256, 0, stream>>>(newh, Wmp, vpart, DD, DD);
    vecmat_red<<<dim3(4,BB), 256, 0, stream>>>(vpart, mproj, DD);
    ln_kernel<<<RR, 256, 0, stream>>>(attb, mproj, g2, be2, attb, nullptr, hn);
    // FFN1: 256^2 8-phase, M=4096 N=4096 K=1024 -> grid 256
    mgemm256<<<256, 512, 0, stream>>>(hn, W1T, 16, 1024, 1, 0, bf1, 1.f, act, nullptr, nullptr, nullptr);
    // FFN2: 256^2 8-phase split-K=4 (bf16 partials), M=4096 N=1024 K=4x1024 -> grid 256
    mgemm256<<<256, 512, 0, stream>>>(act, W2T, 4, 1024, 4, 2, nullptr, 1.f, pb0, pb1, pb2, pb3);
    // out = LN3(sum(partials)+bias+resid)
    ln3f_kernel<<<RR, 256, 0, stream>>>(pb0, pb1, pb2, pb3, bf2, attb, g3, be3, out);
}

// Round 13
// 279.786 us; speedup vs baseline: 1.0679x; 1.0679x over previous
//
#include <hip/hip_runtime.h>
#include <hip/hip_bf16.h>
#include <math.h>

#define BB 2
#define SS 2048
#define DD 1024
#define HH 16
#define RR (BB*SS)
#define KSTRIDE 2064   // padded key stride per (b,h)
#define MB (1024ull*1024ull)

typedef unsigned short u16;
typedef unsigned int u32;
typedef __attribute__((ext_vector_type(8))) short short8v;
typedef __attribute__((ext_vector_type(4))) float f32x4;
typedef __attribute__((ext_vector_type(16))) float f32x16;
typedef __attribute__((ext_vector_type(4))) u16 u16x4;

__device__ __forceinline__ u16 f2bf(float f){
    union { __hip_bfloat16 h; u16 u; } c; c.h = __float2bfloat16(f); return c.u;
}
// packed f32x2 -> bf16x2 in one instruction (dst.lo=bf16(a), dst.hi=bf16(b))
__device__ __forceinline__ u32 cvtpk(float a, float b){
    u32 r;
    asm("v_cvt_pk_bf16_f32 %0, %1, %2" : "=v"(r) : "v"(a), "v"(b));
    return r;
}
__device__ __forceinline__ float exp2_raw(float x){
    float r;
    asm("v_exp_f32 %0, %1" : "=v"(r) : "v"(x));
    return r;
}
__device__ __forceinline__ float bf2f(u16 u){
    union { u32 i; float f; } c; c.i = (u32)u << 16; return c.f;
}
// A&S 7.1.26 erf approximation, |err| <= 1.5e-7
__device__ __forceinline__ float erf_fast(float x){
    float ax = fabsf(x);
    float t = __builtin_amdgcn_rcpf(1.0f + 0.3275911f*ax);
    float y = t*(0.254829592f + t*(-0.284496736f + t*(1.421413741f + t*(-1.453152027f + t*1.061405429f))));
    float r = 1.0f - y*__expf(-ax*ax);
    return copysignf(r, x);
}

#define GLL16(gp, lp) __builtin_amdgcn_global_load_lds( \
    (const __attribute__((address_space(1))) void*)(gp), \
    (__attribute__((address_space(3))) void*)(lp), 16, 0, 0)

#define VMCNT8 asm volatile("s_waitcnt vmcnt(8)" ::: "memory")
#define VMCNT4 asm volatile("s_waitcnt vmcnt(4)" ::: "memory")
#define VMCNT0 asm volatile("s_waitcnt vmcnt(0)" ::: "memory")
#define SBAR   __builtin_amdgcn_s_barrier()
#define SCHEDB __builtin_amdgcn_sched_barrier(0)

// ---------------- LayerNorm ----------------
__global__ __launch_bounds__(256) void ln_kernel(const float* __restrict__ in,
    const float* __restrict__ mproj, const float* __restrict__ g, const float* __restrict__ be,
    float* __restrict__ mixed_out, float* __restrict__ outf, u16* __restrict__ outb)
{
    int row = blockIdx.x; int b = row / SS; int tid = threadIdx.x;
    float4 v = ((const float4*)(in + (size_t)row*DD))[tid];
    if (mproj){
        float4 mp = ((const float4*)(mproj + (size_t)b*DD))[tid];
        v.x+=mp.x; v.y+=mp.y; v.z+=mp.z; v.w+=mp.w;
        ((float4*)(mixed_out + (size_t)row*DD))[tid] = v;
    }
    float s = v.x+v.y+v.z+v.w, s2 = v.x*v.x+v.y*v.y+v.z*v.z+v.w*v.w;
    #pragma unroll
    for (int off=32; off>0; off>>=1){ s += __shfl_down(s,off); s2 += __shfl_down(s2,off); }
    __shared__ float red[2][4];
    if ((tid&63)==0){ red[0][tid>>6]=s; red[1][tid>>6]=s2; }
    __syncthreads();
    float st = red[0][0]+red[0][1]+red[0][2]+red[0][3];
    float s2t= red[1][0]+red[1][1]+red[1][2]+red[1][3];
    float mean = st*(1.f/DD); float var = s2t*(1.f/DD)-mean*mean;
    float rs = rsqrtf(var + 1e-5f);
    float4 gg=((const float4*)g)[tid], bb2=((const float4*)be)[tid];
    float o0=(v.x-mean)*rs*gg.x+bb2.x, o1=(v.y-mean)*rs*gg.y+bb2.y;
    float o2=(v.z-mean)*rs*gg.z+bb2.z, o3=(v.w-mean)*rs*gg.w+bb2.w;
    if (outf){ float4 o={o0,o1,o2,o3}; ((float4*)(outf+(size_t)row*DD))[tid]=o; }
    if (outb){ u16x4 o={f2bf(o0),f2bf(o1),f2bf(o2),f2bf(o3)}; ((u16x4*)(outb+(size_t)row*DD))[tid]=o; }
}

// ---------------- final: y = sum(4 bf16 partials)+bias+resid, out = LN(y) ----------------
__global__ __launch_bounds__(256) void ln3f_kernel(const u16* __restrict__ pb0,
    const u16* __restrict__ pb1, const u16* __restrict__ pb2, const u16* __restrict__ pb3,
    const float* __restrict__ bias, const float* __restrict__ resid,
    const float* __restrict__ g, const float* __restrict__ be, float* __restrict__ out)
{
    int row = blockIdx.x; int tid = threadIdx.x;
    size_t off = (size_t)row*DD;
    u16x4 q0 = ((const u16x4*)(pb0+off))[tid];
    u16x4 q1 = ((const u16x4*)(pb1+off))[tid];
    u16x4 q2 = ((const u16x4*)(pb2+off))[tid];
    u16x4 q3 = ((const u16x4*)(pb3+off))[tid];
    float4 bi = ((const float4*)bias)[tid];
    float4 rs4= ((const float4*)(resid+off))[tid];
    float4 v;
    v.x = bf2f(q0[0])+bf2f(q1[0])+bf2f(q2[0])+bf2f(q3[0]) + bi.x + rs4.x;
    v.y = bf2f(q0[1])+bf2f(q1[1])+bf2f(q2[1])+bf2f(q3[1]) + bi.y + rs4.y;
    v.z = bf2f(q0[2])+bf2f(q1[2])+bf2f(q2[2])+bf2f(q3[2]) + bi.z + rs4.z;
    v.w = bf2f(q0[3])+bf2f(q1[3])+bf2f(q2[3])+bf2f(q3[3]) + bi.w + rs4.w;
    float s = v.x+v.y+v.z+v.w, s2 = v.x*v.x+v.y*v.y+v.z*v.z+v.w*v.w;
    #pragma unroll
    for (int off2=32; off2>0; off2>>=1){ s += __shfl_down(s,off2); s2 += __shfl_down(s2,off2); }
    __shared__ float red[2][4];
    if ((tid&63)==0){ red[0][tid>>6]=s; red[1][tid>>6]=s2; }
    __syncthreads();
    float st = red[0][0]+red[0][1]+red[0][2]+red[0][3];
    float s2t= red[1][0]+red[1][1]+red[1][2]+red[1][3];
    float mean = st*(1.f/DD); float var = s2t*(1.f/DD)-mean*mean;
    float rs = rsqrtf(var + 1e-5f);
    float4 gg=((const float4*)g)[tid], bb2=((const float4*)be)[tid];
    float4 o;
    o.x=(v.x-mean)*rs*gg.x+bb2.x; o.y=(v.y-mean)*rs*gg.y+bb2.y;
    o.z=(v.z-mean)*rs*gg.z+bb2.z; o.w=(v.w-mean)*rs*gg.w+bb2.w;
    ((float4*)(out + off))[tid] = o;
}

// ---------------- merged weight transposes ----------------
__global__ __launch_bounds__(256) void tr6_kernel(const float* __restrict__ Wq, const float* __restrict__ Wk,
    const float* __restrict__ Wv, const float* __restrict__ Wo,
    const float* __restrict__ W1, const float* __restrict__ W2,
    u16* __restrict__ WqkvT, u16* __restrict__ WoT, u16* __restrict__ W1T, u16* __restrict__ W2T)
{
    __shared__ float t[32][33];
    int bid = blockIdx.x;
    const float* in; u16* out; int K, N, n0, k0;
    if (bid < 3072){
        int m = bid >> 10, r = bid & 1023;
        in = (m==0) ? Wq : (m==1) ? Wk : Wv;
        out = WqkvT + (size_t)m*1024*1024;
        K = 1024; N = 1024; n0 = (r & 31)*32; k0 = (r >> 5)*32;
    } else if (bid < 4096){
        int r = bid - 3072;
        in = Wo; out = WoT; K = 1024; N = 1024; n0 = (r & 31)*32; k0 = (r >> 5)*32;
    } else if (bid < 8192){
        int r = bid - 4096;
        in = W1; out = W1T; K = 1024; N = 4096; n0 = (r & 127)*32; k0 = (r >> 7)*32;
    } else {
        int r = bid - 8192;
        in = W2; out = W2T; K = 4096; N = 1024; n0 = (r & 31)*32; k0 = (r >> 5)*32;
    }
    int tx = threadIdx.x & 31, ty = threadIdx.x >> 5;
    #pragma unroll
    for (int i=0;i<4;i++){ int k = ty + i*8; t[k][tx] = in[(size_t)(k0+k)*N + n0 + tx]; }
    __syncthreads();
    #pragma unroll
    for (int i=0;i<4;i++){ int n = ty + i*8; out[(size_t)(n0+n)*K + k0 + tx] = f2bf(t[tx][n]); }
}

// =============== 256x256 8-phase GEMM (T2+T3+T4+T5), 512 threads = 8 waves (2M x 4N) ===============
__global__ __launch_bounds__(512) void mgemm256(const u16* __restrict__ A, const u16* __restrict__ BT,
    int nbx, int Kc, int kchunks, int mode, const float* __restrict__ bias, float scale,
    void* __restrict__ Cout, void* __restrict__ C2a, void* __restrict__ C2b, void* __restrict__ C2c)
{
    __shared__ __align__(16) u16 lds[2][2][2][256*32];
    int tid = threadIdx.x, l = tid&63, w = tid>>6;
    int wr = w>>2, wc = w&3;
    int nwg = gridDim.x, q8 = nwg>>3;
    int bid = blockIdx.x;
    int swz = (bid & 7)*q8 + (bid >> 3);
    int tiles = nwg / kchunks;
    int chunk = swz / tiles;
    int t2 = swz % tiles;
    int by = t2 / nbx, bx = t2 % nbx;
    int bm = by*256, bn = bx*256;
    int lda = Kc*kchunks;
    int koff = chunk*Kc;
    const int NT = Kc >> 6;

    f32x4 acc[8][4];
    #pragma unroll
    for (int i=0;i<8;i++)
        #pragma unroll
        for (int j=0;j<4;j++)
            #pragma unroll
            for (int r=0;r<4;r++) acc[i][j][r]=0.f;

    auto stage_plane = [&](int buf, int op, int ks, int tt){
        const u16* base = op ? BT : A;
        int tile0 = op ? bn : bm;
        #pragma unroll
        for (int i=0;i<2;i++){
            int rbase = (w*2+i)*16;
            int row = rbase + (l>>2);
            int slotlog = (l&3) ^ ((row>>1)&3);
            const u16* g = base + (size_t)(tile0 + row)*lda + koff + tt*64 + ks*32 + slotlog*8;
            GLL16(g, (u16*)&lds[buf][op][ks][0] + rbase*32);
        }
    };
    auto ds_a = [&](int buf, int ks, int ai) -> short8v {
        int row = wr*128 + ai*16 + (l&15);
        int slot = (l>>4) ^ ((row>>1)&3);
        return *(const short8v*)((const char*)&lds[buf][0][ks][0] + row*64 + slot*16);
    };
    auto ds_b = [&](int buf, int ks, int bi) -> short8v {
        int row = wc*64 + bi*16 + (l&15);
        int slot = (l>>4) ^ ((row>>1)&3);
        return *(const short8v*)((const char*)&lds[buf][1][ks][0] + row*64 + slot*16);
    };

    stage_plane(0,0,0,0); stage_plane(0,1,0,0);
    stage_plane(0,0,1,0); stage_plane(0,1,1,0);
    stage_plane(1,0,0,1); stage_plane(1,1,0,1);
    VMCNT8;
    SBAR; SCHEDB;

    for (int t=0; t<NT; t++){
        int buf = t&1, obuf = buf^1;
        bool s1 = (t+1 < NT), s2 = (t+2 < NT);
        short8v b0,b1,b2,b3, a0,a1,a2,a3;
        // ---- Ph0
        b0=ds_b(buf,0,0); b1=ds_b(buf,0,1); b2=ds_b(buf,0,2); b3=ds_b(buf,0,3);
        a0=ds_a(buf,0,0); a1=ds_a(buf,0,1); a2=ds_a(buf,0,2); a3=ds_a(buf,0,3);
        if (s1) stage_plane(obuf,0,1,t+1);
        __builtin_amdgcn_s_setprio(1);
        acc[0][0]=__builtin_amdgcn_mfma_f32_16x16x32_bf16(b0,a0,acc[0][0],0,0,0);
        acc[0][1]=__builtin_amdgcn_mfma_f32_16x16x32_bf16(b1,a0,acc[0][1],0,0,0);
        acc[0][2]=__builtin_amdgcn_mfma_f32_16x16x32_bf16(b2,a0,acc[0][2],0,0,0);
        acc[0][3]=__builtin_amdgcn_mfma_f32_16x16x32_bf16(b3,a0,acc[0][3],0,0,0);
        acc[1][0]=__builtin_amdgcn_mfma_f32_16x16x32_bf16(b0,a1,acc[1][0],0,0,0);
        acc[1][1]=__builtin_amdgcn_mfma_f32_16x16x32_bf16(b1,a1,acc[1][1],0,0,0);
        acc[1][2]=__builtin_amdgcn_mfma_f32_16x16x32_bf16(b2,a1,acc[1][2],0,0,0);
        acc[1][3]=__builtin_amdgcn_mfma_f32_16x16x32_bf16(b3,a1,acc[1][3],0,0,0);
        acc[2][0]=__builtin_amdgcn_mfma_f32_16x16x32_bf16(b0,a2,acc[2][0],0,0,0);
        acc[2][1]=__builtin_amdgcn_mfma_f32_16x16x32_bf16(b1,a2,acc[2][1],0,0,0);
        acc[2][2]=__builtin_amdgcn_mfma_f32_16x16x32_bf16(b2,a2,acc[2][2],0,0,0);
        acc[2][3]=__builtin_amdgcn_mfma_f32_16x16x32_bf16(b3,a2,acc[2][3],0,0,0);
        acc[3][0]=__builtin_amdgcn_mfma_f32_16x16x32_bf16(b0,a3,acc[3][0],0,0,0);
        acc[3][1]=__builtin_amdgcn_mfma_f32_16x16x32_bf16(b1,a3,acc[3][1],0,0,0);
        acc[3][2]=__builtin_amdgcn_mfma_f32_16x16x32_bf16(b2,a3,acc[3][2],0,0,0);
        acc[3][3]=__builtin_amdgcn_mfma_f32_16x16x32_bf16(b3,a3,acc[3][3],0,0,0);
        __builtin_amdgcn_s_setprio(0);
        SBAR; SCHEDB;
        // ---- Ph1
        a0=ds_a(buf,0,4); a1=ds_a(buf,0,5); a2=ds_a(buf,0,6); a3=ds_a(buf,0,7);
        if (s1) stage_plane(obuf,1,1,t+1);
        __builtin_amdgcn_s_setprio(1);
        acc[4][0]=__builtin_amdgcn_mfma_f32_16x16x32_bf16(b0,a0,acc[4][0],0,0,0);
        acc[4][1]=__builtin_amdgcn_mfma_f32_16x16x32_bf16(b1,a0,acc[4][1],0,0,0);
        acc[4][2]=__builtin_amdgcn_mfma_f32_16x16x32_bf16(b2,a0,acc[4][2],0,0,0);
        acc[4][3]=__builtin_amdgcn_mfma_f32_16x16x32_bf16(b3,a0,acc[4][3],0,0,0);
        acc[5][0]=__builtin_amdgcn_mfma_f32_16x16x32_bf16(b0,a1,acc[5][0],0,0,0);
        acc[5][1]=__builtin_amdgcn_mfma_f32_16x16x32_bf16(b1,a1,acc[5][1],0,0,0);
        acc[5][2]=__builtin_amdgcn_mfma_f32_16x16x32_bf16(b2,a1,acc[5][2],0,0,0);
        acc[5][3]=__builtin_amdgcn_mfma_f32_16x16x32_bf16(b3,a1,acc[5][3],0,0,0);
        acc[6][0]=__builtin_amdgcn_mfma_f32_16x16x32_bf16(b0,a2,acc[6][0],0,0,0);
        acc[6][1]=__builtin_amdgcn_mfma_f32_16x16x32_bf16(b1,a2,acc[6][1],0,0,0);
        acc[6][2]=__builtin_amdgcn_mfma_f32_16x16x32_bf16(b2,a2,acc[6][2],0,0,0);
        acc[6][3]=__builtin_amdgcn_mfma_f32_16x16x32_bf16(b3,a2,acc[6][3],0,0,0);
        acc[7][0]=__builtin_amdgcn_mfma_f32_16x16x32_bf16(b0,a3,acc[7][0],0,0,0);
        acc[7][1]=__builtin_amdgcn_mfma_f32_16x16x32_bf16(b1,a3,acc[7][1],0,0,0);
        acc[7][2]=__builtin_amdgcn_mfma_f32_16x16x32_bf16(b2,a3,acc[7][2],0,0,0);
        acc[7][3]=__builtin_amdgcn_mfma_f32_16x16x32_bf16(b3,a3,acc[7][3],0,0,0);
        __builtin_amdgcn_s_setprio(0);
        if (s1) { VMCNT8; } else { VMCNT0; }
        SBAR; SCHEDB;
        // ---- Ph2
        b0=ds_b(buf,1,0); b1=ds_b(buf,1,1); b2=ds_b(buf,1,2); b3=ds_b(buf,1,3);
        a0=ds_a(buf,1,0); a1=ds_a(buf,1,1); a2=ds_a(buf,1,2); a3=ds_a(buf,1,3);
        if (s2) stage_plane(buf,0,0,t+2);
        __builtin_amdgcn_s_setprio(1);
        acc[0][0]=__builtin_amdgcn_mfma_f32_16x16x32_bf16(b0,a0,acc[0][0],0,0,0);
        acc[0][1]=__builtin_amdgcn_mfma_f32_16x16x32_bf16(b1,a0,acc[0][1],0,0,0);
        acc[0][2]=__builtin_amdgcn_mfma_f32_16x16x32_bf16(b2,a0,acc[0][2],0,0,0);
        acc[0][3]=__builtin_amdgcn_mfma_f32_16x16x32_bf16(b3,a0,acc[0][3],0,0,0);
        acc[1][0]=__builtin_amdgcn_mfma_f32_16x16x32_bf16(b0,a1,acc[1][0],0,0,0);
        acc[1][1]=__builtin_amdgcn_mfma_f32_16x16x32_bf16(b1,a1,acc[1][1],0,0,0);
        acc[1][2]=__builtin_amdgcn_mfma_f32_16x16x32_bf16(b2,a1,acc[1][2],0,0,0);
        acc[1][3]=__builtin_amdgcn_mfma_f32_16x16x32_bf16(b3,a1,acc[1][3],0,0,0);
        acc[2][0]=__builtin_amdgcn_mfma_f32_16x16x32_bf16(b0,a2,acc[2][0],0,0,0);
        acc[2][1]=__builtin_amdgcn_mfma_f32_16x16x32_bf16(b1,a2,acc[2][1],0,0,0);
        acc[2][2]=__builtin_amdgcn_mfma_f32_16x16x32_bf16(b2,a2,acc[2][2],0,0,0);
        acc[2][3]=__builtin_amdgcn_mfma_f32_16x16x32_bf16(b3,a2,acc[2][3],0,0,0);
        acc[3][0]=__builtin_amdgcn_mfma_f32_16x16x32_bf16(b0,a3,acc[3][0],0,0,0);
        acc[3][1]=__builtin_amdgcn_mfma_f32_16x16x32_bf16(b1,a3,acc[3][1],0,0,0);
        acc[3][2]=__builtin_amdgcn_mfma_f32_16x16x32_bf16(b2,a3,acc[3][2],0,0,0);
        acc[3][3]=__builtin_amdgcn_mfma_f32_16x16x32_bf16(b3,a3,acc[3][3],0,0,0);
        __builtin_amdgcn_s_setprio(0);
        SBAR; SCHEDB;
        // ---- Ph3
        a0=ds_a(buf,1,4); a1=ds_a(buf,1,5); a2=ds_a(buf,1,6); a3=ds_a(buf,1,7);
        if (s2) stage_plane(buf,1,0,t+2);
        __builtin_amdgcn_s_setprio(1);
        acc[4][0]=__builtin_amdgcn_mfma_f32_16x16x32_bf16(b0,a0,acc[4][0],0,0,0);
        acc[4][1]=__builtin_amdgcn_mfma_f32_16x16x32_bf16(b1,a0,acc[4][1],0,0,0);
        acc[4][2]=__builtin_amdgcn_mfma_f32_16x16x32_bf16(b2,a0,acc[4][2],0,0,0);
        acc[4][3]=__builtin_amdgcn_mfma_f32_16x16x32_bf16(b3,a0,acc[4][3],0,0,0);
        acc[5][0]=__builtin_amdgcn_mfma_f32_16x16x32_bf16(b0,a1,acc[5][0],0,0,0);
        acc[5][1]=__builtin_amdgcn_mfma_f32_16x16x32_bf16(b1,a1,acc[5][1],0,0,0);
        acc[5][2]=__builtin_amdgcn_mfma_f32_16x16x32_bf16(b2,a1,acc[5][2],0,0,0);
        acc[5][3]=__builtin_amdgcn_mfma_f32_16x16x32_bf16(b3,a1,acc[5][3],0,0,0);
        acc[6][0]=__builtin_amdgcn_mfma_f32_16x16x32_bf16(b0,a2,acc[6][0],0,0,0);
        acc[6][1]=__builtin_amdgcn_mfma_f32_16x16x32_bf16(b1,a2,acc[6][1],0,0,0);
        acc[6][2]=__builtin_amdgcn_mfma_f32_16x16x32_bf16(b2,a2,acc[6][2],0,0,0);
        acc[6][3]=__builtin_amdgcn_mfma_f32_16x16x32_bf16(b3,a2,acc[6][3],0,0,0);
        acc[7][0]=__builtin_amdgcn_mfma_f32_16x16x32_bf16(b0,a3,acc[7][0],0,0,0);
        acc[7][1]=__builtin_amdgcn_mfma_f32_16x16x32_bf16(b1,a3,acc[7][1],0,0,0);
        acc[7][2]=__builtin_amdgcn_mfma_f32_16x16x32_bf16(b2,a3,acc[7][2],0,0,0);
        acc[7][3]=__builtin_amdgcn_mfma_f32_16x16x32_bf16(b3,a3,acc[7][3],0,0,0);
        __builtin_amdgcn_s_setprio(0);
        if (s2) { VMCNT8; } else if (s1) { VMCNT4; } else { VMCNT0; }
        SBAR; SCHEDB;
    }

    int N = nbx*256;
    #pragma unroll
    for (int ai=0; ai<8; ai++){
        int m = bm + wr*128 + ai*16 + (l&15);
        #pragma unroll
        for (int bi=0; bi<4; bi++){
            int nb = bn + wc*64 + bi*16 + ((l>>4)<<2);
            f32x4 v = acc[ai][bi];
            if (mode == 0){   // GELU bf16
                float4 bv = *(const float4*)(bias + nb);
                float t0=v[0]+bv.x, t1=v[1]+bv.y, t2=v[2]+bv.z, t3=v[3]+bv.w;
                u16x4 o;
                o[0]=f2bf(0.5f*t0*(1.0f+erf_fast(t0*0.70710678118654752f)));
                o[1]=f2bf(0.5f*t1*(1.0f+erf_fast(t1*0.70710678118654752f)));
                o[2]=f2bf(0.5f*t2*(1.0f+erf_fast(t2*0.70710678118654752f)));
                o[3]=f2bf(0.5f*t3*(1.0f+erf_fast(t3*0.70710678118654752f)));
                *(u16x4*)((u16*)Cout + (size_t)m*N + nb) = o;
            } else if (mode == 1){  // QKV
                if (nb < 1024){
                    u16x4 o;
                    #pragma unroll
                    for (int r=0;r<4;r++) o[r] = f2bf(v[r]*scale);
                    *(u16x4*)((u16*)Cout + (size_t)m*1024 + nb) = o;
                } else if (nb < 2048){
                    int cc = nb-1024; int hh = cc>>6, dh = cc&63;
                    int b2 = m>>11, key = m&2047;
                    u16x4 o;
                    #pragma unroll
                    for (int r=0;r<4;r++) o[r] = f2bf(v[r]);
                    *(u16x4*)((u16*)C2a + ((size_t)(b2*HH+hh)*KSTRIDE + key)*64 + dh) = o;
                } else {
                    int cc = nb-2048; int hh = cc>>6, dh = cc&63;
                    int b2 = m>>11, key = m&2047;
                    #pragma unroll
                    for (int r=0;r<4;r++)
                        ((u16*)C2b)[((size_t)(b2*HH+hh)*64 + dh + r)*KSTRIDE + key] = f2bf(v[r]);
                }
            } else {          // mode 2: bf16 partial per chunk
                u16* pp = (chunk==0) ? (u16*)Cout : (chunk==1) ? (u16*)C2a :
                          (chunk==2) ? (u16*)C2b : (u16*)C2c;
                u16x4 o;
                #pragma unroll
                for (int r=0;r<4;r++) o[r] = f2bf(v[r]);
                *(u16x4*)(pp + (size_t)m*N + nb) = o;
            }
        }
    }
}

// ---------------- 128x128 MFMA GEMM (kept for Wo) ----------------
#define MODE_F32R 3

__global__ __launch_bounds__(256) void mgemm(const u16* __restrict__ A, const u16* __restrict__ BT,
    int nbx, int Kc, int kchunks, int mode,
    const float* __restrict__ bias, const float* __restrict__ resid, float scale,
    void* __restrict__ Cout, void* __restrict__ C2a, void* __restrict__ C2b)
{
    int tid=threadIdx.x, l=tid&63, w=tid>>6;
    int nwg = gridDim.x;
    int qq = nwg >> 3;
    int bid = blockIdx.x;
    int swz = (bid & 7)*qq + (bid >> 3);
    int tiles = nwg / kchunks;
    int chunk = swz / tiles;
    int t2 = swz % tiles;
    int sby = t2 / (nbx*8);
    int rem = t2 - sby*(nbx*8);
    int sbx = rem >> 6;
    int ci  = rem & 63;
    int bx = sbx*8 + (ci&7);
    int by = sby*8 + (ci>>3);

    int bm = by*128, bn = bx*128;
    int N = nbx*128;
    int lda = Kc*kchunks;
    int koff = chunk*Kc;
    int wr = w>>1, wc = w&1;
    f32x4 acc[4][4];
    #pragma unroll
    for(int i=0;i<4;i++)
        #pragma unroll
        for(int j=0;j<4;j++)
            #pragma unroll
            for(int r=0;r<4;r++) acc[i][j][r]=0.f;

    __shared__ __align__(16) u16 Al[2][4096];
    __shared__ __align__(16) u16 Bl[2][4096];
    int srow = (w<<4) + (l>>2);
    int sph  = l&3;
    const int NT = Kc >> 5;

    auto stage = [&](int buf, int kt){
        #pragma unroll
        for (int r=0;r<2;r++){
            int rowA = srow + r*64;
            int sl = sph ^ ((rowA>>1)&3);
            const u16* gA = A + (size_t)(bm+rowA)*lda + koff + kt*32 + sl*8;
            GLL16(gA, (char*)&Al[buf][0] + r*4096 + w*1024);
            const u16* gB = BT + (size_t)(bn+rowA)*lda + koff + kt*32 + sl*8;
            GLL16(gB, (char*)&Bl[buf][0] + r*4096 + w*1024);
        }
    };

    int cur=0;
    stage(0,0);
    __syncthreads();
    for (int kt=0; kt<NT; kt++){
        if (kt+1<NT) stage(cur^1, kt+1);
        short8v af[4], bf[4];
        #pragma unroll
        for (int mi=0;mi<4;mi++){
            int row = wr*64 + mi*16 + (l&15);
            int sl = (l>>4) ^ ((row>>1)&3);
            af[mi] = *(const short8v*)((const char*)&Al[cur][0] + row*64 + sl*16);
        }
        #pragma unroll
        for (int ni=0;ni<4;ni++){
            int row = wc*64 + ni*16 + (l&15);
            int sl = (l>>4) ^ ((row>>1)&3);
            bf[ni] = *(const short8v*)((const char*)&Bl[cur][0] + row*64 + sl*16);
        }
        #pragma unroll
        for (int mi=0;mi<4;mi++)
            #pragma unroll
            for (int ni=0;ni<4;ni++)
                acc[mi][ni] = __builtin_amdgcn_mfma_f32_16x16x32_bf16(bf[ni], af[mi], acc[mi][ni], 0,0,0);
        __syncthreads();
        cur ^= 1;
    }

    #pragma unroll
    for (int mi=0;mi<4;mi++){
        int m = bm + wr*64 + mi*16 + (l&15);
        #pragma unroll
        for (int ni=0;ni<4;ni++){
            int nb = bn + wc*64 + ni*16 + ((l>>4)<<2);
            f32x4 v = acc[mi][ni];
            float4 rs = *(const float4*)(resid + (size_t)m*N + nb);
            float4 o = {v[0]+rs.x, v[1]+rs.y, v[2]+rs.z, v[3]+rs.w};
            *(float4*)((float*)Cout + (size_t)m*N + nb) = o;
        }
    }
}

// ---------------- MFMA flash attention: pipelined, triple-buffer, exp2 softmax (R11 proven) ----------------
__global__ __launch_bounds__(256) void attn_mfma(const u16* __restrict__ Qb, const u16* __restrict__ Kb,
    const u16* __restrict__ VTb, u16* __restrict__ ao)
{
    __shared__ __align__(16) u16 Kl[3][4096];
    __shared__ __align__(16) u16 Vl[3][4096];
    int tid=threadIdx.x, l=tid&63, w=tid>>6;
    int l31=l&31, hi=l>>5;
    int bid = blockIdx.x;
    int xcd = bid & 7, idx = bid >> 3;
    int bh = xcd*4 + (idx>>4);
    int qt = idx & 15;
    int b=bh>>4, h=bh&15;
    int qrow = qt*128 + w*32 + l31;

    const u16* qptr = Qb + (size_t)(b*SS + qrow)*DD + h*64;
    short8v qf[4];
    #pragma unroll
    for (int t=0;t<4;t++) qf[t] = *(const short8v*)(qptr + t*16 + hi*8);

    f32x16 so0, so1;
    #pragma unroll
    for (int i=0;i<16;i++){ so0[i]=0.f; so1[i]=0.f; }
    float l_run=0.f;

    int skey = (w<<3) + (l>>3);
    int ssl  = l&7;
    auto stage = [&](int buf, int kt){
        #pragma unroll
        for (int r=0;r<2;r++){
            int key = skey + r*32;
            int slot = ssl ^ (key&7);
            const u16* gK = Kb + ((size_t)bh*KSTRIDE + kt*64 + key)*64 + slot*8;
            GLL16(gK, (char*)&Kl[buf][0] + r*4096 + w*1024);
            const u16* gV = VTb + ((size_t)bh*64 + key)*KSTRIDE + kt*64 + slot*8;
            GLL16(gV, (char*)&Vl[buf][0] + r*4096 + w*1024);
        }
    };

    auto QK = [&](int bf, f32x16& s0, f32x16& s1){
        #pragma unroll
        for (int i=0;i<16;i++){ s0[i]=0.f; s1[i]=0.f; }
        __builtin_amdgcn_s_setprio(1);
        #pragma unroll
        for (int t=0;t<4;t++){
            int sl = (2*t+hi) ^ (l31&7);
            short8v kf0 = *(const short8v*)((const char*)&Kl[bf][0] + l31*128 + sl*16);
            s0 = __builtin_amdgcn_mfma_f32_32x32x16_bf16(kf0, qf[t], s0, 0,0,0);
            short8v kf1 = *(const short8v*)((const char*)&Kl[bf][0] + (32+l31)*128 + sl*16);
            s1 = __builtin_amdgcn_mfma_f32_32x32x16_bf16(kf1, qf[t], s1, 0,0,0);
        }
        __builtin_amdgcn_s_setprio(0);
    };

    auto SMPV = [&](int bf, f32x16& s0, f32x16& s1){
        float psum = 0.f;
        #pragma unroll
        for (int r=0;r<16;r++){
            float p=exp2_raw(s0[r]); s0[r]=p; psum+=p;
            float q=exp2_raw(s1[r]); s1[r]=q; psum+=q;
        }
        psum += __shfl_xor(psum, 32);
        l_run += psum;
        short8v pf[4];
        #pragma unroll
        for (int t=0;t<4;t++){
            u32 a0,a1,b0,b1;
            if (t==0){ a0=cvtpk(s0[0],s0[1]);   a1=cvtpk(s0[2],s0[3]);   b0=cvtpk(s0[4],s0[5]);   b1=cvtpk(s0[6],s0[7]); }
            else if (t==1){ a0=cvtpk(s0[8],s0[9]);   a1=cvtpk(s0[10],s0[11]); b0=cvtpk(s0[12],s0[13]); b1=cvtpk(s0[14],s0[15]); }
            else if (t==2){ a0=cvtpk(s1[0],s1[1]);   a1=cvtpk(s1[2],s1[3]);   b0=cvtpk(s1[4],s1[5]);   b1=cvtpk(s1[6],s1[7]); }
            else          { a0=cvtpk(s1[8],s1[9]);   a1=cvtpk(s1[10],s1[11]); b0=cvtpk(s1[12],s1[13]); b1=cvtpk(s1[14],s1[15]); }
            union { u32 u[4]; short8v v; } cvt;
#if __has_builtin(__builtin_amdgcn_permlane32_swap)
            auto r0 = __builtin_amdgcn_permlane32_swap(a0, b0, false, false);
            auto r1 = __builtin_amdgcn_permlane32_swap(a1, b1, false, false);
            cvt.u[0] = (u32)r0[0];
            cvt.u[1] = (u32)r1[0];
            cvt.u[2] = (u32)r0[1];
            cvt.u[3] = (u32)r1[1];
#else
            u32 sx0 = hi ? a0 : b0, sx1 = hi ? a1 : b1;
            u32 r0 = (u32)__shfl_xor((int)sx0, 32);
            u32 r1 = (u32)__shfl_xor((int)sx1, 32);
            cvt.u[0] = hi ? r0 : a0;
            cvt.u[1] = hi ? r1 : a1;
            cvt.u[2] = hi ? b0 : r0;
            cvt.u[3] = hi ? b1 : r1;
#endif
            pf[t] = cvt.v;
        }
        __builtin_amdgcn_s_setprio(1);
        #pragma unroll
        for (int t=0;t<4;t++){
            int sl = (2*t+hi) ^ (l31&7);
            short8v vf0 = *(const short8v*)((const char*)&Vl[bf][0] + l31*128 + sl*16);
            so0 = __builtin_amdgcn_mfma_f32_32x32x16_bf16(vf0, pf[t], so0, 0,0,0);
            short8v vf1 = *(const short8v*)((const char*)&Vl[bf][0] + (32+l31)*128 + sl*16);
            so1 = __builtin_amdgcn_mfma_f32_32x32x16_bf16(vf1, pf[t], so1, 0,0,0);
        }
        __builtin_amdgcn_s_setprio(0);
    };

    const int NTILE = 33;
    int bufA = 0, bufB = 1, bufC = 2;
    stage(0, 0);
    stage(1, 1);
    __syncthreads();

    f32x16 sA0, sA1, sB0, sB1;
    QK(bufA, sA0, sA1);

    auto ITER = [&](f32x16& c0, f32x16& c1, f32x16& n0, f32x16& n1, int t){
        if (t+2 < NTILE) stage(bufC, t+2);
        QK(bufB, n0, n1);
        SMPV(bufA, c0, c1);
        __syncthreads();
        int tmp = bufA; bufA = bufB; bufB = bufC; bufC = tmp;
    };
    #pragma unroll 1
    for (int tt=0; tt<16; tt++){
        ITER(sA0, sA1, sB0, sB1, 2*tt);
        ITER(sB0, sB1, sA0, sA1, 2*tt+1);
    }
    #pragma unroll
    for (int r=0;r<16;r++){
        int k0 = 2048 + (r&3) + 8*(r>>2) + 4*hi;
        if (k0 >= 2049) sA0[r] = -1e30f;
        sA1[r] = -1e30f;
    }
    SMPV(bufA, sA0, sA1);

    float inv = 1.f / l_run;
    u16* aop = ao + (size_t)(b*SS + qrow)*DD + h*64;
    #pragma unroll
    for (int rg=0; rg<4; rg++){
        int dh0 = rg*8 + 4*hi;
        u16x4 o0, o1;
        #pragma unroll
        for (int j=0;j<4;j++){ o0[j]=f2bf(so0[rg*4+j]*inv); o1[j]=f2bf(so1[rg*4+j]*inv); }
        *(u16x4*)(aop + dh0) = o0;
        *(u16x4*)(aop + 32 + dh0) = o1;
    }
}

// ---------------- split-K matvec ----------------
__global__ __launch_bounds__(256) void vecmat_part(const float* __restrict__ vec,
    const float* __restrict__ W, float* __restrict__ part, int K, int N)
{
    int b = blockIdx.z, kc = blockIdx.y;
    int j = blockIdx.x*256 + threadIdx.x;
    int k0 = kc * (K >> 3);
    float acc = 0.0f;
    #pragma unroll 4
    for (int k = k0; k < k0 + (K >> 3); k++)
        acc += vec[(size_t)b*K + k] * W[(size_t)k*N + j];
    part[((size_t)b*8 + kc)*N + j] = acc;
}

__global__ __launch_bounds__(256) void vecmat_red(const float* __restrict__ part,
    float* __restrict__ out, int N)
{
    int b = blockIdx.y;
    int j = blockIdx.x*256 + threadIdx.x;
    float acc = 0.0f;
    #pragma unroll
    for (int kc = 0; kc < 8; kc++) acc += part[((size_t)b*8 + kc)*N + j];
    out[(size_t)b*N + j] = acc;
}

__global__ __launch_bounds__(256) void vecmat2_part(const float* __restrict__ vec,
    const float* __restrict__ Wa, const float* __restrict__ Wb, float* __restrict__ part)
{
    int b = blockIdx.z, kc = blockIdx.y;
    int j = blockIdx.x*256 + threadIdx.x;
    int k0 = kc * 128;
    float accA = 0.0f, accB = 0.0f;
    #pragma unroll 4
    for (int k = k0; k < k0 + 128; k++){
        float v = vec[(size_t)b*DD + k];
        accA += v * Wa[(size_t)k*DD + j];
        accB += v * Wb[(size_t)k*DD + j];
    }
    part[((size_t)b*8 + kc)*2048 + j] = accA;
    part[((size_t)b*8 + kc)*2048 + 1024 + j] = accB;
}

// ---------------- K/V memory-token fixup (fused 8-chunk reduce) ----------------
__global__ __launch_bounds__(256) void fixup_kernel(const float* __restrict__ v2part,
    u16* __restrict__ Kb, u16* __restrict__ VTb)
{
    int idx = blockIdx.x*256 + threadIdx.x;   // 0..2047
    int b = idx>>10, j = idx&1023; int h=j>>6, dh=j&63; int bh=b*HH+h;
    float km = 0.f, vm = 0.f;
    #pragma unroll
    for (int kc = 0; kc < 8; kc++){
        km += v2part[((size_t)b*8 + kc)*2048 + j];
        vm += v2part[((size_t)b*8 + kc)*2048 + 1024 + j];
    }
    Kb[((size_t)bh*KSTRIDE + 2048)*64 + dh] = f2bf(km);
    VTb[((size_t)bh*64 + dh)*KSTRIDE + 2048] = f2bf(vm);
}

__global__ __launch_bounds__(256) void pool1_kernel(const float* __restrict__ att, float* __restrict__ ppart)
{
    int b = blockIdx.y, sc = blockIdx.x;
    int tid = threadIdx.x;
    float4 acc = {0,0,0,0};
    for (int s = 0; s < 32; s++) {
        int row = b*SS + sc*32 + s;
        float4 v = ((const float4*)(att + (size_t)row*DD))[tid];
        acc.x += v.x; acc.y += v.y; acc.z += v.z; acc.w += v.w;
    }
    ((float4*)(ppart + ((size_t)b*64 + sc)*DD))[tid] = acc;
}

__global__ __launch_bounds__(256) void pool2_kernel(const float* __restrict__ ppart, float* __restrict__ pooled)
{
    int b = blockIdx.y;
    int j = blockIdx.x*256 + threadIdx.x;
    float acc = 0.0f;
    for (int sc = 0; sc < 64; sc++) acc += ppart[((size_t)b*64 + sc)*DD + j];
    pooled[(size_t)b*DD + j] = acc * (1.0f/SS);
}

__global__ __launch_bounds__(256) void gates_part(const float* __restrict__ pooled,
    const float* __restrict__ h, const float* __restrict__ Wih, const float* __restrict__ Whh,
    float* __restrict__ part)
{
    int b = blockIdx.z, kc = blockIdx.y;
    int j = blockIdx.x*256 + threadIdx.x;
    int k0 = kc * 64;
    float acc = 0.0f;
    #pragma unroll 4
    for (int k = k0; k < k0 + 64; k++)
        acc += pooled[(size_t)b*DD + k] * Wih[(size_t)k*4*DD + j]
             + h[(size_t)b*DD + k]      * Whh[(size_t)k*4*DD + j];
    part[((size_t)b*16 + kc)*4*DD + j] = acc;
}

__device__ __forceinline__ float sigmoidf_(float x) { return 1.0f / (1.0f + __expf(-x)); }

__global__ __launch_bounds__(256) void lstm_kernel(const float* __restrict__ gpart,
    const float* __restrict__ b_ih, const float* __restrict__ b_hh,
    const float* __restrict__ c, float* __restrict__ newh_ws, float* __restrict__ out_tail)
{
    int idx = blockIdx.x*256 + threadIdx.x;
    int b = idx >> 10, d = idx & 1023;
    float sI = b_ih[d]          + b_hh[d];
    float sF = b_ih[DD + d]     + b_hh[DD + d];
    float sG = b_ih[2*DD + d]   + b_hh[2*DD + d];
    float sO = b_ih[3*DD + d]   + b_hh[3*DD + d];
    #pragma unroll
    for (int kc = 0; kc < 16; kc++){
        const float* gp = gpart + ((size_t)b*16 + kc)*4*DD;
        sI += gp[d]; sF += gp[DD + d]; sG += gp[2*DD + d]; sO += gp[3*DD + d];
    }
    float ig = sigmoidf_(sI);
    float fg = sigmoidf_(sF);
    float gg = tanhf(sG);
    float og = sigmoidf_(sO);
    float nc = fg * c[idx] + ig * gg;
    float nh = og * tanhf(nc);
    newh_ws[idx] = nh;
    out_tail[idx] = nh;
    out_tail[BB*DD + idx] = nc;
}

// ---------------- launch ----------------
extern "C" void kernel_launch(void* const* d_in, const int* in_sizes, int n_in,
                              void* d_out, int out_size, void* d_ws, size_t ws_size,
                              hipStream_t stream) {
    const float* x    = (const float*)d_in[0];
    const float* h    = (const float*)d_in[1];
    const float* c    = (const float*)d_in[2];
    const float* Wq   = (const float*)d_in[3];
    const float* Wk   = (const float*)d_in[4];
    const float* Wv   = (const float*)d_in[5];
    const float* Wo   = (const float*)d_in[6];
    const float* Wmk  = (const float*)d_in[7];
    const float* Wmv  = (const float*)d_in[8];
    const float* Wih  = (const float*)d_in[9];
    const float* Whh  = (const float*)d_in[10];
    const float* b_ih = (const float*)d_in[11];
    const float* b_hh = (const float*)d_in[12];
    const float* W1   = (const float*)d_in[13];
    const float* bf1  = (const float*)d_in[14];
    const float* W2   = (const float*)d_in[15];
    const float* bf2  = (const float*)d_in[16];
    const float* g1   = (const float*)d_in[17];
    const float* be1  = (const float*)d_in[18];
    const float* g2   = (const float*)d_in[19];
    const float* be2  = (const float*)d_in[20];
    const float* g3   = (const float*)d_in[21];
    const float* be3  = (const float*)d_in[22];
    const float* Wmp  = (const float*)d_in[23];

    float* out = (float*)d_out;
    char* wsb  = (char*)d_ws;

    u16*   xn   = (u16*)(wsb + 0);        // 8MB  [0,8)
    u16*   hn   = (u16*)(wsb + 8*MB);     // 8MB  [8,16)
    u16*   pb0  = (u16*)(wsb + 0);        // FFN2 partial (xn dead)
    u16*   pb1  = (u16*)(wsb + 8*MB);     // FFN2 partial (hn dead)
    u16*   Qbuf = (u16*)(wsb + 16*MB);
    u16*   Kbuf = (u16*)(wsb + 24*MB);
    u16*   VTb  = (u16*)(wsb + 33*MB);
    u16*   act  = (u16*)(wsb + 16*MB);    // 32MB overlay [16,48)
    u16*   ao   = (u16*)(wsb + 48*MB);    // 8MB
    u16*   pb2  = (u16*)(wsb + 48*MB);    // FFN2 partial (ao dead)
    float* attb = (float*)(wsb + 56*MB);  // 16MB [56,72)
    u16*   WqkvT= (u16*)(wsb + 72*MB);    // 6MB
    u16*   WoT  = (u16*)(wsb + 78*MB);    // 2MB
    u16*   W1T  = (u16*)(wsb + 80*MB);    // 8MB
    u16*   pb3  = (u16*)(wsb + 80*MB);    // FFN2 partial (W1T dead)
    u16*   W2T  = (u16*)(wsb + 88*MB);    // 8MB
    float* sm   = (float*)(wsb + 96*MB);
    float* pooled  = sm;
    float* newh    = pooled + 2048;
    float* mproj   = newh + 2048;
    float* vpart   = mproj + 2048;
    float* v2part  = vpart + 16384;
    float* gpart   = v2part + 32768;
    float* ppart   = gpart + 131072;

    tr6_kernel<<<12288, 256, 0, stream>>>(Wq, Wk, Wv, Wo, W1, W2, WqkvT, WoT, W1T, W2T);

    ln_kernel<<<RR, 256, 0, stream>>>(x, nullptr, g1, be1, nullptr, nullptr, xn);
    vecmat2_part<<<dim3(4,8,BB), 256, 0, stream>>>(h, Wmk, Wmv, v2part);
    // fused QKV projection: 256^2 8-phase, M=4096 N=3072 K=1024 -> grid 192
    mgemm256<<<192, 512, 0, stream>>>(xn, WqkvT, 12, 1024, 1, 1, nullptr,
                                      0.125f*1.44269504088896f, Qbuf, Kbuf, VTb, nullptr);
    fixup_kernel<<<8, 256, 0, stream>>>(v2part, Kbuf, VTb);
    // attention (512 blocks, XCD-grouped, pipelined triple-buffer — R11 proven)
    attn_mfma<<<512, 256, 0, stream>>>(Qbuf, Kbuf, VTb, ao);
    // attended = x + ao @ Wo (128^2 path)
    mgemm<<<8*32, 256, 0, stream>>>(ao, WoT, 8, 1024, 1, MODE_F32R, nullptr, x, 1.f, attb, nullptr, nullptr);
    pool1_kernel<<<dim3(64,BB), 256, 0, stream>>>(attb, ppart);
    pool2_kernel<<<dim3(4,BB), 256, 0, stream>>>(ppart, pooled);
    gates_part<<<dim3(16,16,BB), 256, 0, stream>>>(pooled, h, Wih, Whh, gpart);
    lstm_kernel<<<8, 256, 0, stream>>>(gpart, b_ih, b_hh, c, newh, out + (size_t)RR*DD);
    vecmat_part<<<dim3(4,8,BB), 256, 0, stream>>>(newh, Wmp, vpart, DD, DD);
    vecmat_red<<<dim3(4,BB), 256, 0, stream>>>(vpart, mproj, DD);
    ln_kernel<<<RR, 256, 0, stream>>>(attb, mproj, g2, be2, attb, nullptr, hn);
    // FFN1: 256^2 8-phase, M=4096 N=4096 K=1024 -> grid 256
    mgemm256<<<256, 512, 0, stream>>>(hn, W1T, 16, 1024, 1, 0, bf1, 1.f, act, nullptr, nullptr, nullptr);
    // FFN2: 256^2 8-phase split-K=4 (bf16 partials), M=4096 N=1024 K=4x1024 -> grid 256
    mgemm256<<<256, 512, 0, stream>>>(act, W2T, 4, 1024, 4, 2, nullptr, 1.f, pb0, pb1, pb2, pb3);
    // out = LN3(sum(partials)+bias+resid)
    ln3f_kernel<<<RR, 256, 0, stream>>>(pb0, pb1, pb2, pb3, bf2, attb, g3, be3, out);
}